// Round 6
// baseline (82.593 us; speedup 1.0000x reference)
//
#include <hip/hip_runtime.h>
#include <math.h>

#define N 512
#define TILE 32
#define INV2PI 0.15915494309189535f

// ---- packed (2-element-per-lane) float2 helpers: lowered to v_pk_*_f32 ----
__device__ __forceinline__ float2 pset(float a, float b) { return make_float2(a, b); }
__device__ __forceinline__ float2 psplat(float a) { return make_float2(a, a); }
__device__ __forceinline__ float2 p_sub(float2 a, float2 b) { return make_float2(a.x - b.x, a.y - b.y); }
__device__ __forceinline__ float2 p_mul(float2 a, float2 b) { return make_float2(a.x * b.x, a.y * b.y); }
__device__ __forceinline__ float2 p_fma(float2 a, float2 b, float2 c) {
    return make_float2(fmaf(a.x, b.x, c.x), fmaf(a.y, b.y, c.y));
}
// a*b - c*d  (fused)
__device__ __forceinline__ float2 p_fmsub(float2 a, float2 b, float2 c, float2 d) {
    return make_float2(fmaf(a.x, b.x, -(c.x * d.x)), fmaf(a.y, b.y, -(c.y * d.y)));
}
__device__ __forceinline__ float2 p_clamp1(float2 a) {
    return make_float2(fminf(1.f, fmaxf(-1.f, a.x)), fminf(1.f, fmaxf(-1.f, a.y)));
}
__device__ __forceinline__ float2 p_rsq(float2 a) {
    return make_float2(__builtin_amdgcn_rsqf(a.x), __builtin_amdgcn_rsqf(a.y));
}

struct F3P { float2 x, y, z; };

__device__ __forceinline__ F3P pp_sub(F3P a, F3P b) {
    return {p_sub(a.x, b.x), p_sub(a.y, b.y), p_sub(a.z, b.z)};
}
__device__ __forceinline__ F3P pp_cross(F3P a, F3P b) {
    F3P c;
    c.x = p_fmsub(a.y, b.z, a.z, b.y);
    c.y = p_fmsub(a.z, b.x, a.x, b.z);
    c.z = p_fmsub(a.x, b.y, a.y, b.x);
    return c;
}
__device__ __forceinline__ float2 pp_dot(F3P a, F3P b) {
    return p_fma(a.x, b.x, p_fma(a.y, b.y, p_mul(a.z, b.z)));
}

// Abramowitz-Stegun 4.4.45, |err| <= 5e-5; polynomial packed, sqrt per half.
__device__ __forceinline__ float2 p_asin(float2 v) {
    float2 ax = make_float2(fabsf(v.x), fabsf(v.y));
    float2 p = p_fma(ax, psplat(-0.0187293f), psplat(0.0742610f));
    p = p_fma(ax, p, psplat(-0.2121144f));
    p = p_fma(ax, p, psplat(1.5707288f));
    float2 s = make_float2(__builtin_amdgcn_sqrtf(1.0f - ax.x), __builtin_amdgcn_sqrtf(1.0f - ax.y));
    float2 r = make_float2(1.5707963267948966f - s.x * p.x, 1.5707963267948966f - s.y * p.y);
    return make_float2(copysignf(r.x, v.x), copysignf(r.y, v.y));
}

// Two independent writhe evaluations, one in each float2 half.
__device__ __forceinline__ float2 wr_core2(F3P p0, F3P p1, F3P p2, F3P p3) {
    // Displacement normalization cancels in normalized crosses and in the sign term.
    F3P d0 = pp_sub(p2, p0), d1 = pp_sub(p3, p0), d2 = pp_sub(p2, p1), d3 = pp_sub(p3, p1);

    F3P c0 = pp_cross(d0, d1);
    F3P c1 = pp_cross(d1, d3);
    F3P c2 = pp_cross(d3, d2);
    F3P c3 = pp_cross(d2, d0);

    float2 r0 = p_rsq(pp_dot(c0, c0));
    float2 r1 = p_rsq(pp_dot(c1, c1));
    float2 r2 = p_rsq(pp_dot(c2, c2));
    float2 r3 = p_rsq(pp_dot(c3, c3));

    float2 t01 = p_clamp1(p_mul(pp_dot(c0, c1), p_mul(r0, r1)));
    float2 t12 = p_clamp1(p_mul(pp_dot(c1, c2), p_mul(r1, r2)));
    float2 t23 = p_clamp1(p_mul(pp_dot(c2, c3), p_mul(r2, r3)));
    float2 t30 = p_clamp1(p_mul(pp_dot(c3, c0), p_mul(r3, r0)));

    float2 a01 = p_asin(t01), a12 = p_asin(t12), a23 = p_asin(t23), a30 = p_asin(t30);
    float2 omega = make_float2(a01.x + a12.x + a23.x + a30.x, a01.y + a12.y + a23.y + a30.y);

    F3P e = pp_cross(pp_sub(p3, p2), pp_sub(p1, p0));
    float2 sv = pp_dot(e, d0);
    float sgx = (sv.x > 0.f) ? 1.f : ((sv.x < 0.f) ? -1.f : 0.f);
    float sgy = (sv.y > 0.f) ? 1.f : ((sv.y < 0.f) ? -1.f : 0.f);

    return make_float2(omega.x * sgx * INV2PI, omega.y * sgy * INV2PI);
}

__device__ __forceinline__ F3P pack_pt(const float4* __restrict__ xs4, int i0, int i1) {
    float4 a = xs4[i0];
    float4 b = xs4[i1];
    F3P r;
    r.x = pset(a.x, b.x);
    r.y = pset(a.y, b.y);
    r.z = pset(a.z, b.z);
    return r;
}

// Branchless per-element index rule (resolves the reference's two sequential
// overlapping scatters): out(lo,hi): lo>=1 & hi>=lo+2 -> segment (lo-1, hi-1);
// lo==0 & 2<=hi<=510 -> segment (0, hi). Indices clamped so speculative LDS
// loads stay in-bounds; validity applied by select afterwards.
__device__ __forceinline__ void elem_idx(int gi, int gj, int& a, int& b, bool& valid) {
    const int lo = min(gi, gj), hi = max(gi, gj);
    const bool z = (lo == 0);
    a = z ? 0 : (lo - 1);
    b = z ? min(hi, 510) : (hi - 1);
    valid = z ? ((hi >= 2) && (hi <= 510)) : (hi >= lo + 2);
}

// One block per (upper-triangle tile pair, batch). Each lane computes TWO output
// elements (rows r and r+16, same column) packed in float2 halves -> v_pk_*_f32.
// Single branchless path for all tiles: exactly 2 inlines of wr_core2, no
// divergent branches in the hot loop. __launch_bounds__(256,4): VGPR<=128,
// 4 blocks/CU for latency hiding of the rsq/sqrt dependency chains.
__global__ __launch_bounds__(256, 4) void writhe_tile(const float* __restrict__ x,
                                                      float* __restrict__ out) {
    __shared__ __align__(16) float4 xs4[N];
    __shared__ float ts[TILE][TILE + 1];

    const int batch = blockIdx.y;

    // Coalesced float4 global read, stride-3 -> stride-4 repack into LDS.
    {
        const float4* src = (const float4*)(x + (size_t)batch * (N * 3));
        float* xsf = (float*)xs4;
        for (int i = threadIdx.x; i < (N * 3) / 4; i += blockDim.x) {
            float4 g = src[i];
            const int base = 4 * i;
            float vv[4] = {g.x, g.y, g.z, g.w};
#pragma unroll
            for (int j = 0; j < 4; ++j) {
                const int e = base + j;
                xsf[(e / 3) * 4 + (e % 3)] = vv[j];
            }
        }
    }

    // blockIdx.x -> (ti, tj), ti <= tj, among 16x16 tiles (136 pairs).
    int p = blockIdx.x;
    int ti = 0;
    while (p >= (N / TILE) - ti) { p -= (N / TILE) - ti; ++ti; }
    const int tj = ti + p;
    const bool diag = (ti == tj);

    __syncthreads();

    const int c = threadIdx.x & 31;
    const int r0 = threadIdx.x >> 5;
    const int gj = tj * TILE + c;
    float* ob = out + (size_t)batch * (N * N);

#pragma unroll
    for (int k = 0; k < 2; ++k) {
        const int rA = r0 + 8 * k;   // half .x row
        const int rB = rA + 16;      // half .y row
        const int giA = ti * TILE + rA;
        const int giB = ti * TILE + rB;

        int aA, bA, aB, bB;
        bool vA, vB;
        elem_idx(giA, gj, aA, bA, vA);
        elem_idx(giB, gj, aB, bB, vB);

        F3P P0 = pack_pt(xs4, aA, aB);
        F3P P1 = pack_pt(xs4, aA + 1, aB + 1);
        F3P P2 = pack_pt(xs4, bA, bB);
        F3P P3 = pack_pt(xs4, bA + 1, bB + 1);

        float2 wr = wr_core2(P0, P1, P2, P3);
        const float vxA = vA ? wr.x : 0.f;
        const float vxB = vB ? wr.y : 0.f;

        ob[(size_t)giA * N + gj] = vxA;
        ob[(size_t)giB * N + gj] = vxB;
        if (!diag) {
            ts[rA][c] = vxA;
            ts[rB][c] = vxB;
        }
    }

    if (!diag) {
        __syncthreads();
#pragma unroll
        for (int k = 0; k < 4; ++k) {
            const int r = r0 + 8 * k;
            ob[(size_t)(tj * TILE + r) * N + (ti * TILE + c)] = ts[c][r];
        }
    }
}

extern "C" void kernel_launch(void* const* d_in, const int* in_sizes, int n_in,
                              void* d_out, int out_size, void* d_ws, size_t ws_size,
                              hipStream_t stream) {
    const float* x = (const float*)d_in[0];
    float* out = (float*)d_out;
    const int B = in_sizes[0] / (N * 3);

    const int ntiles = N / TILE;                   // 16
    const int npairs = ntiles * (ntiles + 1) / 2;  // 136

    dim3 block(256);
    dim3 grid(npairs, B);
    writhe_tile<<<grid, block, 0, stream>>>(x, out);
}

// Round 7
// 82.245 us; speedup vs baseline: 1.0042x; 1.0042x over previous
//
#include <hip/hip_runtime.h>
#include <math.h>

#define N 512
#define TILE 32
#define INV2PI 0.15915494309189535f

// ---- packed (2-element-per-lane) float2 helpers: lowered to v_pk_*_f32 ----
__device__ __forceinline__ float2 pset(float a, float b) { return make_float2(a, b); }
__device__ __forceinline__ float2 psplat(float a) { return make_float2(a, a); }
__device__ __forceinline__ float2 p_sub(float2 a, float2 b) { return make_float2(a.x - b.x, a.y - b.y); }
__device__ __forceinline__ float2 p_mul(float2 a, float2 b) { return make_float2(a.x * b.x, a.y * b.y); }
__device__ __forceinline__ float2 p_fma(float2 a, float2 b, float2 c) {
    return make_float2(fmaf(a.x, b.x, c.x), fmaf(a.y, b.y, c.y));
}
// a*b - c*d  (fused)
__device__ __forceinline__ float2 p_fmsub(float2 a, float2 b, float2 c, float2 d) {
    return make_float2(fmaf(a.x, b.x, -(c.x * d.x)), fmaf(a.y, b.y, -(c.y * d.y)));
}
__device__ __forceinline__ float2 p_clamp1(float2 a) {
    return make_float2(fminf(1.f, fmaxf(-1.f, a.x)), fminf(1.f, fmaxf(-1.f, a.y)));
}
__device__ __forceinline__ float2 p_rsq(float2 a) {
    return make_float2(__builtin_amdgcn_rsqf(a.x), __builtin_amdgcn_rsqf(a.y));
}

struct F3P { float2 x, y, z; };

__device__ __forceinline__ F3P pp_sub(F3P a, F3P b) {
    return {p_sub(a.x, b.x), p_sub(a.y, b.y), p_sub(a.z, b.z)};
}
__device__ __forceinline__ F3P pp_cross(F3P a, F3P b) {
    F3P c;
    c.x = p_fmsub(a.y, b.z, a.z, b.y);
    c.y = p_fmsub(a.z, b.x, a.x, b.z);
    c.z = p_fmsub(a.x, b.y, a.y, b.x);
    return c;
}
__device__ __forceinline__ float2 pp_dot(F3P a, F3P b) {
    return p_fma(a.x, b.x, p_fma(a.y, b.y, p_mul(a.z, b.z)));
}

// Abramowitz-Stegun 4.4.45, |err| <= 5e-5; polynomial packed, sqrt per half.
__device__ __forceinline__ float2 p_asin(float2 v) {
    float2 ax = make_float2(fabsf(v.x), fabsf(v.y));
    float2 p = p_fma(ax, psplat(-0.0187293f), psplat(0.0742610f));
    p = p_fma(ax, p, psplat(-0.2121144f));
    p = p_fma(ax, p, psplat(1.5707288f));
    float2 s = make_float2(__builtin_amdgcn_sqrtf(1.0f - ax.x), __builtin_amdgcn_sqrtf(1.0f - ax.y));
    float2 r = make_float2(1.5707963267948966f - s.x * p.x, 1.5707963267948966f - s.y * p.y);
    return make_float2(copysignf(r.x, v.x), copysignf(r.y, v.y));
}

// Two independent writhe evaluations, one in each float2 half.
__device__ __forceinline__ float2 wr_core2(F3P p0, F3P p1, F3P p2, F3P p3) {
    // Displacement normalization cancels in normalized crosses and in the sign term.
    F3P d0 = pp_sub(p2, p0), d1 = pp_sub(p3, p0), d2 = pp_sub(p2, p1), d3 = pp_sub(p3, p1);

    F3P c0 = pp_cross(d0, d1);
    F3P c1 = pp_cross(d1, d3);
    F3P c2 = pp_cross(d3, d2);
    F3P c3 = pp_cross(d2, d0);

    float2 r0 = p_rsq(pp_dot(c0, c0));
    float2 r1 = p_rsq(pp_dot(c1, c1));
    float2 r2 = p_rsq(pp_dot(c2, c2));
    float2 r3 = p_rsq(pp_dot(c3, c3));

    float2 t01 = p_clamp1(p_mul(pp_dot(c0, c1), p_mul(r0, r1)));
    float2 t12 = p_clamp1(p_mul(pp_dot(c1, c2), p_mul(r1, r2)));
    float2 t23 = p_clamp1(p_mul(pp_dot(c2, c3), p_mul(r2, r3)));
    float2 t30 = p_clamp1(p_mul(pp_dot(c3, c0), p_mul(r3, r0)));

    float2 a01 = p_asin(t01), a12 = p_asin(t12), a23 = p_asin(t23), a30 = p_asin(t30);
    float2 omega = make_float2(a01.x + a12.x + a23.x + a30.x, a01.y + a12.y + a23.y + a30.y);

    F3P e = pp_cross(pp_sub(p3, p2), pp_sub(p1, p0));
    float2 sv = pp_dot(e, d0);
    float sgx = (sv.x > 0.f) ? 1.f : ((sv.x < 0.f) ? -1.f : 0.f);
    float sgy = (sv.y > 0.f) ? 1.f : ((sv.y < 0.f) ? -1.f : 0.f);

    return make_float2(omega.x * sgx * INV2PI, omega.y * sgy * INV2PI);
}

__device__ __forceinline__ F3P pack_pt(const float4* __restrict__ xs4, int i0, int i1) {
    float4 a = xs4[i0];
    float4 b = xs4[i1];
    F3P r;
    r.x = pset(a.x, b.x);
    r.y = pset(a.y, b.y);
    r.z = pset(a.z, b.z);
    return r;
}

__device__ __forceinline__ F3P splat_pt(const float4* __restrict__ xs4, int i) {
    float4 a = xs4[i];
    F3P r;
    r.x = psplat(a.x);
    r.y = psplat(a.y);
    r.z = psplat(a.z);
    return r;
}

// Branchless per-element index rule (resolves the reference's two sequential
// overlapping scatters): out(lo,hi): lo>=1 & hi>=lo+2 -> segment (lo-1, hi-1);
// lo==0 & 2<=hi<=510 -> segment (0, hi). Indices clamped so speculative LDS
// loads stay in-bounds; validity applied by select afterwards.
__device__ __forceinline__ void elem_idx(int gi, int gj, int& a, int& b, bool& valid) {
    const int lo = min(gi, gj), hi = max(gi, gj);
    const bool z = (lo == 0);
    a = z ? 0 : (lo - 1);
    b = z ? min(hi, 510) : (hi - 1);
    valid = z ? ((hi >= 2) && (hi <= 510)) : (hi >= lo + 2);
}

// One block per (upper-triangle tile pair, batch).
// Fast path (1 <= ti < tj, 105/136 blocks): each lane packs TWO COLUMNS
// (c, c+16) of one row -> column points loaded ONCE per thread (shared by both
// k-calls), row points are wave-broadcast splats. 8 ds_read_b128 per 4 elements
// vs 16 in the row-packed layout. Generic path (diag + ti==0) unchanged from R6.
__global__ __launch_bounds__(256) void writhe_tile(const float* __restrict__ x,
                                                   float* __restrict__ out) {
    __shared__ __align__(16) float4 xs4[N];
    __shared__ float ts[TILE][TILE + 1];

    const int batch = blockIdx.y;

    // Coalesced float4 global read, stride-3 -> stride-4 repack into LDS.
    {
        const float4* src = (const float4*)(x + (size_t)batch * (N * 3));
        float* xsf = (float*)xs4;
        for (int i = threadIdx.x; i < (N * 3) / 4; i += blockDim.x) {
            float4 g = src[i];
            const int base = 4 * i;
            float vv[4] = {g.x, g.y, g.z, g.w};
#pragma unroll
            for (int j = 0; j < 4; ++j) {
                const int e = base + j;
                xsf[(e / 3) * 4 + (e % 3)] = vv[j];
            }
        }
    }

    // blockIdx.x -> (ti, tj), ti <= tj, among 16x16 tiles (136 pairs).
    int p = blockIdx.x;
    int ti = 0;
    while (p >= (N / TILE) - ti) { p -= (N / TILE) - ti; ++ti; }
    const int tj = ti + p;
    const bool diag = (ti == tj);

    __syncthreads();

    float* ob = out + (size_t)batch * (N * N);

    if (ti >= 1 && !diag) {
        // ---- fast path: index rule is unconditionally (gi-1, gj-1) ----
        const int c = threadIdx.x & 15;   // column within half-tile
        const int r = threadIdx.x >> 4;   // row in [0,16)
        const int gj0 = tj * TILE + c;
        const int gj1 = gj0 + 16;

        // Column points: loaded once, shared by both k-calls.
        const F3P P2 = pack_pt(xs4, gj0 - 1, gj1 - 1);
        const F3P P3 = pack_pt(xs4, gj0, gj1);

#pragma unroll
        for (int k = 0; k < 2; ++k) {
            const int rr = r + 16 * k;
            const int gi = ti * TILE + rr;
            const F3P P0 = splat_pt(xs4, gi - 1);
            const F3P P1 = splat_pt(xs4, gi);
            float2 wr = wr_core2(P0, P1, P2, P3);
            // gj1 - gi >= 17 always; gj0 - gi can be 1 only for adjacent tiles.
            const float vx = (gj0 >= gi + 2) ? wr.x : 0.f;
            const float vy = wr.y;
            ob[(size_t)gi * N + gj0] = vx;
            ob[(size_t)gi * N + gj1] = vy;
            ts[rr][c] = vx;
            ts[rr][c + 16] = vy;
        }

        __syncthreads();
#pragma unroll
        for (int k = 0; k < 4; ++k) {
            const int r2 = (threadIdx.x >> 5) + 8 * k;
            const int c2 = threadIdx.x & 31;
            ob[(size_t)(tj * TILE + r2) * N + (ti * TILE + c2)] = ts[c2][r2];
        }
    } else {
        // ---- generic path (diag + ti==0 tiles): proven R6 body ----
        const int c = threadIdx.x & 31;
        const int r0 = threadIdx.x >> 5;
        const int gj = tj * TILE + c;

#pragma unroll
        for (int k = 0; k < 2; ++k) {
            const int rA = r0 + 8 * k;
            const int rB = rA + 16;
            const int giA = ti * TILE + rA;
            const int giB = ti * TILE + rB;

            int aA, bA, aB, bB;
            bool vA, vB;
            elem_idx(giA, gj, aA, bA, vA);
            elem_idx(giB, gj, aB, bB, vB);

            F3P P0 = pack_pt(xs4, aA, aB);
            F3P P1 = pack_pt(xs4, aA + 1, aB + 1);
            F3P P2 = pack_pt(xs4, bA, bB);
            F3P P3 = pack_pt(xs4, bA + 1, bB + 1);

            float2 wr = wr_core2(P0, P1, P2, P3);
            const float vxA = vA ? wr.x : 0.f;
            const float vxB = vB ? wr.y : 0.f;

            ob[(size_t)giA * N + gj] = vxA;
            ob[(size_t)giB * N + gj] = vxB;
            if (!diag) {
                ts[rA][c] = vxA;
                ts[rB][c] = vxB;
            }
        }

        if (!diag) {
            __syncthreads();
#pragma unroll
            for (int k = 0; k < 4; ++k) {
                const int r2 = r0 + 8 * k;
                ob[(size_t)(tj * TILE + r2) * N + (ti * TILE + c)] = ts[c][r2];
            }
        }
    }
}

extern "C" void kernel_launch(void* const* d_in, const int* in_sizes, int n_in,
                              void* d_out, int out_size, void* d_ws, size_t ws_size,
                              hipStream_t stream) {
    const float* x = (const float*)d_in[0];
    float* out = (float*)d_out;
    const int B = in_sizes[0] / (N * 3);

    const int ntiles = N / TILE;                   // 16
    const int npairs = ntiles * (ntiles + 1) / 2;  // 136

    dim3 block(256);
    dim3 grid(npairs, B);
    writhe_tile<<<grid, block, 0, stream>>>(x, out);
}

// Round 8
// 79.723 us; speedup vs baseline: 1.0360x; 1.0316x over previous
//
#include <hip/hip_runtime.h>
#include <math.h>

#define N 512
#define TILE 32
#define INV2PI 0.15915494309189535f

// ---- packed (2-element-per-lane) float2 helpers: lowered to v_pk_*_f32 ----
__device__ __forceinline__ float2 pset(float a, float b) { return make_float2(a, b); }
__device__ __forceinline__ float2 psplat(float a) { return make_float2(a, a); }
__device__ __forceinline__ float2 p_sub(float2 a, float2 b) { return make_float2(a.x - b.x, a.y - b.y); }
__device__ __forceinline__ float2 p_mul(float2 a, float2 b) { return make_float2(a.x * b.x, a.y * b.y); }
__device__ __forceinline__ float2 p_fma(float2 a, float2 b, float2 c) {
    return make_float2(fmaf(a.x, b.x, c.x), fmaf(a.y, b.y, c.y));
}
// a*b - c*d  (fused)
__device__ __forceinline__ float2 p_fmsub(float2 a, float2 b, float2 c, float2 d) {
    return make_float2(fmaf(a.x, b.x, -(c.x * d.x)), fmaf(a.y, b.y, -(c.y * d.y)));
}
__device__ __forceinline__ float2 p_rsq(float2 a) {
    return make_float2(__builtin_amdgcn_rsqf(a.x), __builtin_amdgcn_rsqf(a.y));
}

struct F3P { float2 x, y, z; };

__device__ __forceinline__ F3P pp_sub(F3P a, F3P b) {
    return {p_sub(a.x, b.x), p_sub(a.y, b.y), p_sub(a.z, b.z)};
}
__device__ __forceinline__ F3P pp_cross(F3P a, F3P b) {
    F3P c;
    c.x = p_fmsub(a.y, b.z, a.z, b.y);
    c.y = p_fmsub(a.z, b.x, a.x, b.z);
    c.z = p_fmsub(a.x, b.y, a.y, b.x);
    return c;
}
__device__ __forceinline__ float2 pp_dot(F3P a, F3P b) {
    return p_fma(a.x, b.x, p_fma(a.y, b.y, p_mul(a.z, b.z)));
}

// Fused clamp + Abramowitz-Stegun 4.4.45 asin + sign restore. |err| <= 5e-5.
// ax = min(|t|,1): abs is a free VOP3 input modifier; upper clamp needed for sqrt.
__device__ __forceinline__ float2 p_asin_clamped(float2 t) {
    float2 ax = make_float2(fminf(fabsf(t.x), 1.f), fminf(fabsf(t.y), 1.f));
    float2 p = p_fma(ax, psplat(-0.0187293f), psplat(0.0742610f));
    p = p_fma(ax, p, psplat(-0.2121144f));
    p = p_fma(ax, p, psplat(1.5707288f));
    float sx = __builtin_amdgcn_sqrtf(1.0f - ax.x);
    float sy = __builtin_amdgcn_sqrtf(1.0f - ax.y);
    float rx = fmaf(-sx, p.x, 1.5707963267948966f);
    float ry = fmaf(-sy, p.y, 1.5707963267948966f);
    return make_float2(copysignf(rx, t.x), copysignf(ry, t.y));
}

// Two independent writhe evaluations, one in each float2 half.
__device__ __forceinline__ float2 wr_core2(F3P p0, F3P p1, F3P p2, F3P p3) {
    // Displacement normalization cancels in normalized crosses and in the sign term.
    F3P d0 = pp_sub(p2, p0), d1 = pp_sub(p3, p0), d2 = pp_sub(p2, p1), d3 = pp_sub(p3, p1);

    F3P c0 = pp_cross(d0, d1);
    F3P c1 = pp_cross(d1, d3);
    F3P c2 = pp_cross(d3, d2);
    F3P c3 = pp_cross(d2, d0);

    float2 q0 = pp_dot(c0, c0);
    float2 q1 = pp_dot(c1, c1);
    float2 q2 = pp_dot(c2, c2);
    float2 q3 = pp_dot(c3, c3);

    // t_ij = (c_i . c_j) * rsq(|c_i|^2 * |c_j|^2)
    float2 t01 = p_mul(pp_dot(c0, c1), p_rsq(p_mul(q0, q1)));
    float2 t12 = p_mul(pp_dot(c1, c2), p_rsq(p_mul(q1, q2)));
    float2 t23 = p_mul(pp_dot(c2, c3), p_rsq(p_mul(q2, q3)));
    float2 t30 = p_mul(pp_dot(c3, c0), p_rsq(p_mul(q3, q0)));

    float2 a01 = p_asin_clamped(t01), a12 = p_asin_clamped(t12);
    float2 a23 = p_asin_clamped(t23), a30 = p_asin_clamped(t30);
    float2 omega = make_float2(a01.x + a12.x + a23.x + a30.x,
                               a01.y + a12.y + a23.y + a30.y);

    // Sign term: cross(p3-p2, p1-p0).d0 == -(d1 . c3)  [c3 = d2 x d0 reused].
    // wr = omega*sign(sv)/(2pi) = (omega ^ signbit(svn)) * (-1/(2pi)), svn = -sv.
    // Exact for svn != 0 (measure zero on random normal inputs).
    float2 svn = pp_dot(d1, c3);
    float ox = __int_as_float(__float_as_int(omega.x) ^
                              (__float_as_int(svn.x) & 0x80000000));
    float oy = __int_as_float(__float_as_int(omega.y) ^
                              (__float_as_int(svn.y) & 0x80000000));
    return make_float2(ox * -INV2PI, oy * -INV2PI);
}

__device__ __forceinline__ F3P pack_pt(const float4* __restrict__ xs4, int i0, int i1) {
    float4 a = xs4[i0];
    float4 b = xs4[i1];
    F3P r;
    r.x = pset(a.x, b.x);
    r.y = pset(a.y, b.y);
    r.z = pset(a.z, b.z);
    return r;
}

__device__ __forceinline__ F3P splat_pt(const float4* __restrict__ xs4, int i) {
    float4 a = xs4[i];
    F3P r;
    r.x = psplat(a.x);
    r.y = psplat(a.y);
    r.z = psplat(a.z);
    return r;
}

// Branchless per-element index rule (resolves the reference's two sequential
// overlapping scatters): out(lo,hi): lo>=1 & hi>=lo+2 -> segment (lo-1, hi-1);
// lo==0 & 2<=hi<=510 -> segment (0, hi). Indices clamped so speculative LDS
// loads stay in-bounds; validity applied by select afterwards.
__device__ __forceinline__ void elem_idx(int gi, int gj, int& a, int& b, bool& valid) {
    const int lo = min(gi, gj), hi = max(gi, gj);
    const bool z = (lo == 0);
    a = z ? 0 : (lo - 1);
    b = z ? min(hi, 510) : (hi - 1);
    valid = z ? ((hi >= 2) && (hi <= 510)) : (hi >= lo + 2);
}

// One block per (upper-triangle tile pair, batch).
// Fast path (1 <= ti < tj): two columns packed per lane, column points loaded
// once per thread; row points wave-broadcast. Generic path: diag + ti==0.
__global__ __launch_bounds__(256) void writhe_tile(const float* __restrict__ x,
                                                   float* __restrict__ out) {
    __shared__ __align__(16) float4 xs4[N];
    __shared__ float ts[TILE][TILE + 1];

    const int batch = blockIdx.y;

    // Coalesced float4 global read, stride-3 -> stride-4 repack into LDS.
    {
        const float4* src = (const float4*)(x + (size_t)batch * (N * 3));
        float* xsf = (float*)xs4;
        for (int i = threadIdx.x; i < (N * 3) / 4; i += blockDim.x) {
            float4 g = src[i];
            const int base = 4 * i;
            float vv[4] = {g.x, g.y, g.z, g.w};
#pragma unroll
            for (int j = 0; j < 4; ++j) {
                const int e = base + j;
                xsf[(e / 3) * 4 + (e % 3)] = vv[j];
            }
        }
    }

    // blockIdx.x -> (ti, tj), ti <= tj, among 16x16 tiles (136 pairs).
    int p = blockIdx.x;
    int ti = 0;
    while (p >= (N / TILE) - ti) { p -= (N / TILE) - ti; ++ti; }
    const int tj = ti + p;
    const bool diag = (ti == tj);

    __syncthreads();

    float* ob = out + (size_t)batch * (N * N);

    if (ti >= 1 && !diag) {
        // ---- fast path: index rule is unconditionally (gi-1, gj-1) ----
        const int c = threadIdx.x & 15;   // column within half-tile
        const int r = threadIdx.x >> 4;   // row in [0,16)
        const int gj0 = tj * TILE + c;
        const int gj1 = gj0 + 16;

        // Column points: loaded once, shared by both k-calls.
        const F3P P2 = pack_pt(xs4, gj0 - 1, gj1 - 1);
        const F3P P3 = pack_pt(xs4, gj0, gj1);

#pragma unroll
        for (int k = 0; k < 2; ++k) {
            const int rr = r + 16 * k;
            const int gi = ti * TILE + rr;
            const F3P P0 = splat_pt(xs4, gi - 1);
            const F3P P1 = splat_pt(xs4, gi);
            float2 wr = wr_core2(P0, P1, P2, P3);
            // gj1 - gi >= 17 always; gj0 - gi can be 1 only for adjacent tiles.
            const float vx = (gj0 >= gi + 2) ? wr.x : 0.f;
            const float vy = wr.y;
            ob[(size_t)gi * N + gj0] = vx;
            ob[(size_t)gi * N + gj1] = vy;
            ts[rr][c] = vx;
            ts[rr][c + 16] = vy;
        }

        __syncthreads();
#pragma unroll
        for (int k = 0; k < 4; ++k) {
            const int r2 = (threadIdx.x >> 5) + 8 * k;
            const int c2 = threadIdx.x & 31;
            ob[(size_t)(tj * TILE + r2) * N + (ti * TILE + c2)] = ts[c2][r2];
        }
    } else {
        // ---- generic path (diag + ti==0 tiles) ----
        const int c = threadIdx.x & 31;
        const int r0 = threadIdx.x >> 5;
        const int gj = tj * TILE + c;

#pragma unroll
        for (int k = 0; k < 2; ++k) {
            const int rA = r0 + 8 * k;
            const int rB = rA + 16;
            const int giA = ti * TILE + rA;
            const int giB = ti * TILE + rB;

            int aA, bA, aB, bB;
            bool vA, vB;
            elem_idx(giA, gj, aA, bA, vA);
            elem_idx(giB, gj, aB, bB, vB);

            F3P P0 = pack_pt(xs4, aA, aB);
            F3P P1 = pack_pt(xs4, aA + 1, aB + 1);
            F3P P2 = pack_pt(xs4, bA, bB);
            F3P P3 = pack_pt(xs4, bA + 1, bB + 1);

            float2 wr = wr_core2(P0, P1, P2, P3);
            const float vxA = vA ? wr.x : 0.f;
            const float vxB = vB ? wr.y : 0.f;

            ob[(size_t)giA * N + gj] = vxA;
            ob[(size_t)giB * N + gj] = vxB;
            if (!diag) {
                ts[rA][c] = vxA;
                ts[rB][c] = vxB;
            }
        }

        if (!diag) {
            __syncthreads();
#pragma unroll
            for (int k = 0; k < 4; ++k) {
                const int r2 = r0 + 8 * k;
                ob[(size_t)(tj * TILE + r2) * N + (ti * TILE + c)] = ts[c][r2];
            }
        }
    }
}

extern "C" void kernel_launch(void* const* d_in, const int* in_sizes, int n_in,
                              void* d_out, int out_size, void* d_ws, size_t ws_size,
                              hipStream_t stream) {
    const float* x = (const float*)d_in[0];
    float* out = (float*)d_out;
    const int B = in_sizes[0] / (N * 3);

    const int ntiles = N / TILE;                   // 16
    const int npairs = ntiles * (ntiles + 1) / 2;  // 136

    dim3 block(256);
    dim3 grid(npairs, B);
    writhe_tile<<<grid, block, 0, stream>>>(x, out);
}

// Round 9
// 79.325 us; speedup vs baseline: 1.0412x; 1.0050x over previous
//
#include <hip/hip_runtime.h>
#include <math.h>

#define N 512
#define TILE 32
#define INV2PI 0.15915494309189535f

// ---- packed (2-element-per-lane) float2 helpers: lowered to v_pk_*_f32 ----
__device__ __forceinline__ float2 pset(float a, float b) { return make_float2(a, b); }
__device__ __forceinline__ float2 psplat(float a) { return make_float2(a, a); }
__device__ __forceinline__ float2 p_sub(float2 a, float2 b) { return make_float2(a.x - b.x, a.y - b.y); }
__device__ __forceinline__ float2 p_mul(float2 a, float2 b) { return make_float2(a.x * b.x, a.y * b.y); }
__device__ __forceinline__ float2 p_fma(float2 a, float2 b, float2 c) {
    return make_float2(fmaf(a.x, b.x, c.x), fmaf(a.y, b.y, c.y));
}
// a*b - c*d  (fused)
__device__ __forceinline__ float2 p_fmsub(float2 a, float2 b, float2 c, float2 d) {
    return make_float2(fmaf(a.x, b.x, -(c.x * d.x)), fmaf(a.y, b.y, -(c.y * d.y)));
}
__device__ __forceinline__ float2 p_rsq(float2 a) {
    return make_float2(__builtin_amdgcn_rsqf(a.x), __builtin_amdgcn_rsqf(a.y));
}

struct F3P { float2 x, y, z; };

__device__ __forceinline__ F3P pp_sub(F3P a, F3P b) {
    return {p_sub(a.x, b.x), p_sub(a.y, b.y), p_sub(a.z, b.z)};
}
__device__ __forceinline__ F3P pp_cross(F3P a, F3P b) {
    F3P c;
    c.x = p_fmsub(a.y, b.z, a.z, b.y);
    c.y = p_fmsub(a.z, b.x, a.x, b.z);
    c.z = p_fmsub(a.x, b.y, a.y, b.x);
    return c;
}
__device__ __forceinline__ float2 pp_dot(F3P a, F3P b) {
    return p_fma(a.x, b.x, p_fma(a.y, b.y, p_mul(a.z, b.z)));
}

// Fused clamp + Abramowitz-Stegun 4.4.45 asin + sign restore. |err| <= 5e-5.
__device__ __forceinline__ float2 p_asin_clamped(float2 t) {
    float2 ax = make_float2(fminf(fabsf(t.x), 1.f), fminf(fabsf(t.y), 1.f));
    float2 p = p_fma(ax, psplat(-0.0187293f), psplat(0.0742610f));
    p = p_fma(ax, p, psplat(-0.2121144f));
    p = p_fma(ax, p, psplat(1.5707288f));
    float sx = __builtin_amdgcn_sqrtf(1.0f - ax.x);
    float sy = __builtin_amdgcn_sqrtf(1.0f - ax.y);
    float rx = fmaf(-sx, p.x, 1.5707963267948966f);
    float ry = fmaf(-sy, p.y, 1.5707963267948966f);
    return make_float2(copysignf(rx, t.x), copysignf(ry, t.y));
}

// Two independent writhe evaluations, one per float2 half.
// Liveness-ordered: each cross is consumed (self-dot + neighbor dots)
// immediately, so d3/d2/d0 and c1/c2 retire early -> peak ~55 VGPR, allowing
// 6 blocks/CU under __launch_bounds__(256,6).
__device__ __forceinline__ float2 wr_core2(F3P p0, F3P p1, F3P p2, F3P p3) {
    F3P d0 = pp_sub(p2, p0), d1 = pp_sub(p3, p0), d2 = pp_sub(p2, p1), d3 = pp_sub(p3, p1);

    F3P c0 = pp_cross(d0, d1);
    float2 q0 = pp_dot(c0, c0);

    F3P c1 = pp_cross(d1, d3);
    float2 q1 = pp_dot(c1, c1);
    float2 n01 = pp_dot(c0, c1);

    F3P c2 = pp_cross(d3, d2);           // d3 dead after this
    float2 q2 = pp_dot(c2, c2);
    float2 n12 = pp_dot(c1, c2);         // c1 dead

    F3P c3 = pp_cross(d2, d0);           // d2, d0 dead
    float2 q3 = pp_dot(c3, c3);
    float2 n23 = pp_dot(c2, c3);         // c2 dead
    float2 n30 = pp_dot(c3, c0);         // c0 dead
    float2 svn = pp_dot(d1, c3);         // d1, c3 dead; svn = -(sign dot)

    float2 t01 = p_mul(n01, p_rsq(p_mul(q0, q1)));
    float2 t12 = p_mul(n12, p_rsq(p_mul(q1, q2)));
    float2 t23 = p_mul(n23, p_rsq(p_mul(q2, q3)));
    float2 t30 = p_mul(n30, p_rsq(p_mul(q3, q0)));

    float2 a01 = p_asin_clamped(t01), a12 = p_asin_clamped(t12);
    float2 a23 = p_asin_clamped(t23), a30 = p_asin_clamped(t30);
    float2 omega = make_float2(a01.x + a12.x + a23.x + a30.x,
                               a01.y + a12.y + a23.y + a30.y);

    // wr = omega*sign(-svn)/(2pi) = (omega ^ signbit(svn)) * (-1/(2pi)).
    float ox = __int_as_float(__float_as_int(omega.x) ^
                              (__float_as_int(svn.x) & 0x80000000));
    float oy = __int_as_float(__float_as_int(omega.y) ^
                              (__float_as_int(svn.y) & 0x80000000));
    return make_float2(ox * -INV2PI, oy * -INV2PI);
}

__device__ __forceinline__ F3P pack_pt(const float4* __restrict__ xs4, int i0, int i1) {
    float4 a = xs4[i0];
    float4 b = xs4[i1];
    F3P r;
    r.x = pset(a.x, b.x);
    r.y = pset(a.y, b.y);
    r.z = pset(a.z, b.z);
    return r;
}

__device__ __forceinline__ F3P splat_pt(const float4* __restrict__ xs4, int i) {
    float4 a = xs4[i];
    F3P r;
    r.x = psplat(a.x);
    r.y = psplat(a.y);
    r.z = psplat(a.z);
    return r;
}

// Branchless per-element index rule: out(lo,hi): lo>=1 & hi>=lo+2 -> segment
// (lo-1,hi-1); lo==0 & 2<=hi<=510 -> segment (0,hi). Clamped for speculative loads.
__device__ __forceinline__ void elem_idx(int gi, int gj, int& a, int& b, bool& valid) {
    const int lo = min(gi, gj), hi = max(gi, gj);
    const bool z = (lo == 0);
    a = z ? 0 : (lo - 1);
    b = z ? min(hi, 510) : (hi - 1);
    valid = z ? ((hi >= 2) && (hi <= 510)) : (hi >= lo + 2);
}

// One block per (upper-triangle tile pair, batch).
// __launch_bounds__(256,6): cap VGPR at ~85 -> 6 blocks/CU (75% occupancy) for
// latency hiding of the cross->dot->rsq->asin chains (R6's (256,4) was neutral
// because the kernel already fit 128 VGPR; stalls point at wave shortage).
__global__ __launch_bounds__(256, 6) void writhe_tile(const float* __restrict__ x,
                                                      float* __restrict__ out) {
    __shared__ __align__(16) float4 xs4[N];
    __shared__ float ts[TILE][TILE + 1];

    const int batch = blockIdx.y;

    // Coalesced float4 global read, stride-3 -> stride-4 repack into LDS.
    {
        const float4* src = (const float4*)(x + (size_t)batch * (N * 3));
        float* xsf = (float*)xs4;
        for (int i = threadIdx.x; i < (N * 3) / 4; i += blockDim.x) {
            float4 g = src[i];
            const int base = 4 * i;
            float vv[4] = {g.x, g.y, g.z, g.w};
#pragma unroll
            for (int j = 0; j < 4; ++j) {
                const int e = base + j;
                xsf[(e / 3) * 4 + (e % 3)] = vv[j];
            }
        }
    }

    // blockIdx.x -> (ti, tj), ti <= tj, among 16x16 tiles (136 pairs).
    int p = blockIdx.x;
    int ti = 0;
    while (p >= (N / TILE) - ti) { p -= (N / TILE) - ti; ++ti; }
    const int tj = ti + p;
    const bool diag = (ti == tj);

    __syncthreads();

    float* ob = out + (size_t)batch * (N * N);

    if (ti >= 1 && !diag) {
        // ---- fast path: index rule is unconditionally (gi-1, gj-1) ----
        const int c = threadIdx.x & 15;   // column within half-tile
        const int r = threadIdx.x >> 4;   // row in [0,16)
        const int gj0 = tj * TILE + c;
        const int gj1 = gj0 + 16;

        const F3P P2 = pack_pt(xs4, gj0 - 1, gj1 - 1);
        const F3P P3 = pack_pt(xs4, gj0, gj1);

#pragma unroll
        for (int k = 0; k < 2; ++k) {
            const int rr = r + 16 * k;
            const int gi = ti * TILE + rr;
            const F3P P0 = splat_pt(xs4, gi - 1);
            const F3P P1 = splat_pt(xs4, gi);
            float2 wr = wr_core2(P0, P1, P2, P3);
            const float vx = (gj0 >= gi + 2) ? wr.x : 0.f;
            const float vy = wr.y;
            ob[(size_t)gi * N + gj0] = vx;
            ob[(size_t)gi * N + gj1] = vy;
            ts[rr][c] = vx;
            ts[rr][c + 16] = vy;
        }

        __syncthreads();
#pragma unroll
        for (int k = 0; k < 4; ++k) {
            const int r2 = (threadIdx.x >> 5) + 8 * k;
            const int c2 = threadIdx.x & 31;
            ob[(size_t)(tj * TILE + r2) * N + (ti * TILE + c2)] = ts[c2][r2];
        }
    } else {
        // ---- generic path (diag + ti==0 tiles) ----
        const int c = threadIdx.x & 31;
        const int r0 = threadIdx.x >> 5;
        const int gj = tj * TILE + c;

#pragma unroll
        for (int k = 0; k < 2; ++k) {
            const int rA = r0 + 8 * k;
            const int rB = rA + 16;
            const int giA = ti * TILE + rA;
            const int giB = ti * TILE + rB;

            int aA, bA, aB, bB;
            bool vA, vB;
            elem_idx(giA, gj, aA, bA, vA);
            elem_idx(giB, gj, aB, bB, vB);

            F3P P0 = pack_pt(xs4, aA, aB);
            F3P P1 = pack_pt(xs4, aA + 1, aB + 1);
            F3P P2 = pack_pt(xs4, bA, bB);
            F3P P3 = pack_pt(xs4, bA + 1, bB + 1);

            float2 wr = wr_core2(P0, P1, P2, P3);
            const float vxA = vA ? wr.x : 0.f;
            const float vxB = vB ? wr.y : 0.f;

            ob[(size_t)giA * N + gj] = vxA;
            ob[(size_t)giB * N + gj] = vxB;
            if (!diag) {
                ts[rA][c] = vxA;
                ts[rB][c] = vxB;
            }
        }

        if (!diag) {
            __syncthreads();
#pragma unroll
            for (int k = 0; k < 4; ++k) {
                const int r2 = r0 + 8 * k;
                ob[(size_t)(tj * TILE + r2) * N + (ti * TILE + c)] = ts[c][r2];
            }
        }
    }
}

extern "C" void kernel_launch(void* const* d_in, const int* in_sizes, int n_in,
                              void* d_out, int out_size, void* d_ws, size_t ws_size,
                              hipStream_t stream) {
    const float* x = (const float*)d_in[0];
    float* out = (float*)d_out;
    const int B = in_sizes[0] / (N * 3);

    const int ntiles = N / TILE;                   // 16
    const int npairs = ntiles * (ntiles + 1) / 2;  // 136

    dim3 block(256);
    dim3 grid(npairs, B);
    writhe_tile<<<grid, block, 0, stream>>>(x, out);
}

// Round 10
// 79.096 us; speedup vs baseline: 1.0442x; 1.0029x over previous
//
#include <hip/hip_runtime.h>
#include <math.h>

#define N 512
#define TILE 32
#define TSTRIDE 34  // ts row stride in dwords: even -> aligned float2 writes, 2-way-conflict reads (free)
#define INV2PI 0.15915494309189535f

// ---- packed (2-element-per-lane) float2 helpers: lowered to v_pk_*_f32 ----
__device__ __forceinline__ float2 pset(float a, float b) { return make_float2(a, b); }
__device__ __forceinline__ float2 psplat(float a) { return make_float2(a, a); }
__device__ __forceinline__ float2 p_sub(float2 a, float2 b) { return make_float2(a.x - b.x, a.y - b.y); }
__device__ __forceinline__ float2 p_mul(float2 a, float2 b) { return make_float2(a.x * b.x, a.y * b.y); }
__device__ __forceinline__ float2 p_fma(float2 a, float2 b, float2 c) {
    return make_float2(fmaf(a.x, b.x, c.x), fmaf(a.y, b.y, c.y));
}
// a*b - c*d (fused)
__device__ __forceinline__ float2 p_fmsub(float2 a, float2 b, float2 c, float2 d) {
    return make_float2(fmaf(a.x, b.x, -(c.x * d.x)), fmaf(a.y, b.y, -(c.y * d.y)));
}
__device__ __forceinline__ float2 p_rsq(float2 a) {
    return make_float2(__builtin_amdgcn_rsqf(a.x), __builtin_amdgcn_rsqf(a.y));
}

struct F3P { float2 x, y, z; };

__device__ __forceinline__ F3P pp_sub(F3P a, F3P b) {
    return {p_sub(a.x, b.x), p_sub(a.y, b.y), p_sub(a.z, b.z)};
}
__device__ __forceinline__ F3P pp_cross(F3P a, F3P b) {
    F3P c;
    c.x = p_fmsub(a.y, b.z, a.z, b.y);
    c.y = p_fmsub(a.z, b.x, a.x, b.z);
    c.z = p_fmsub(a.x, b.y, a.y, b.x);
    return c;
}
__device__ __forceinline__ float2 pp_dot(F3P a, F3P b) {
    return p_fma(a.x, b.x, p_fma(a.y, b.y, p_mul(a.z, b.z)));
}

// Fused clamp + Abramowitz-Stegun 4.4.45 asin + sign restore. |err| <= 5e-5.
__device__ __forceinline__ float2 p_asin_clamped(float2 t) {
    float2 ax = make_float2(fminf(fabsf(t.x), 1.f), fminf(fabsf(t.y), 1.f));
    float2 p = p_fma(ax, psplat(-0.0187293f), psplat(0.0742610f));
    p = p_fma(ax, p, psplat(-0.2121144f));
    p = p_fma(ax, p, psplat(1.5707288f));
    float sx = __builtin_amdgcn_sqrtf(1.0f - ax.x);
    float sy = __builtin_amdgcn_sqrtf(1.0f - ax.y);
    float rx = fmaf(-sx, p.x, 1.5707963267948966f);
    float ry = fmaf(-sy, p.y, 1.5707963267948966f);
    return make_float2(copysignf(rx, t.x), copysignf(ry, t.y));
}

// Two independent writhe evaluations, one per float2 half.
// Reformulated: u=p1-p0, v=p3-p2, d0=p2-p0;
//   c0=d0xd1=d0xv, c3=d2xd0=d0xu, w=uxv, c1=d1xd3=w-c3, c2=d3xd2=w-c0,
//   sign dot: -cross(v,u).d0 = w.d0  (all identities verified symbolically).
// 3 crosses + 2 vector adds replace 4 crosses + 4 subs; d1/d2/d3 never built.
__device__ __forceinline__ float2 wr_core2(F3P p0, F3P p1, F3P p2, F3P p3) {
    F3P u = pp_sub(p1, p0);
    F3P v = pp_sub(p3, p2);
    F3P d0 = pp_sub(p2, p0);

    F3P c0 = pp_cross(d0, v);
    F3P c3 = pp_cross(d0, u);
    F3P w  = pp_cross(u, v);
    F3P c1 = {p_sub(w.x, c3.x), p_sub(w.y, c3.y), p_sub(w.z, c3.z)};
    F3P c2 = {p_sub(w.x, c0.x), p_sub(w.y, c0.y), p_sub(w.z, c0.z)};

    float2 svn = pp_dot(w, d0);  // = -(sign dot); sign(sv) = sign(-svn)

    float2 q0 = pp_dot(c0, c0);
    float2 q1 = pp_dot(c1, c1);
    float2 q2 = pp_dot(c2, c2);
    float2 q3 = pp_dot(c3, c3);

    float2 t01 = p_mul(pp_dot(c0, c1), p_rsq(p_mul(q0, q1)));
    float2 t12 = p_mul(pp_dot(c1, c2), p_rsq(p_mul(q1, q2)));
    float2 t23 = p_mul(pp_dot(c2, c3), p_rsq(p_mul(q2, q3)));
    float2 t30 = p_mul(pp_dot(c3, c0), p_rsq(p_mul(q3, q0)));

    float2 a01 = p_asin_clamped(t01), a12 = p_asin_clamped(t12);
    float2 a23 = p_asin_clamped(t23), a30 = p_asin_clamped(t30);
    float2 omega = make_float2(a01.x + a12.x + a23.x + a30.x,
                               a01.y + a12.y + a23.y + a30.y);

    // wr = omega*sign(-svn)/(2pi) = (omega ^ signbit(svn)) * (-1/(2pi)).
    float ox = __int_as_float(__float_as_int(omega.x) ^
                              (__float_as_int(svn.x) & 0x80000000));
    float oy = __int_as_float(__float_as_int(omega.y) ^
                              (__float_as_int(svn.y) & 0x80000000));
    return make_float2(ox * -INV2PI, oy * -INV2PI);
}

__device__ __forceinline__ F3P pack_pt4(float4 a, float4 b) {
    F3P r;
    r.x = pset(a.x, b.x);
    r.y = pset(a.y, b.y);
    r.z = pset(a.z, b.z);
    return r;
}
__device__ __forceinline__ F3P pack_pt(const float4* __restrict__ xs4, int i0, int i1) {
    return pack_pt4(xs4[i0], xs4[i1]);
}
__device__ __forceinline__ F3P splat_pt(const float4* __restrict__ xs4, int i) {
    float4 a = xs4[i];
    F3P r;
    r.x = psplat(a.x);
    r.y = psplat(a.y);
    r.z = psplat(a.z);
    return r;
}

// Branchless per-element index rule: out(lo,hi): lo>=1 & hi>=lo+2 -> segment
// (lo-1,hi-1); lo==0 & 2<=hi<=510 -> segment (0,hi). Clamped for speculative loads.
__device__ __forceinline__ void elem_idx(int gi, int gj, int& a, int& b, bool& valid) {
    const int lo = min(gi, gj), hi = max(gi, gj);
    const bool z = (lo == 0);
    a = z ? 0 : (lo - 1);
    b = z ? min(hi, 510) : (hi - 1);
    valid = z ? ((hi >= 2) && (hi <= 510)) : (hi >= lo + 2);
}

// One block per (upper-triangle tile pair, batch).
// Fast path (1 <= ti < tj): halves = ADJACENT columns (gj, gj+1) -> 3 unique
// column-point loads, one aligned float2 store per row-pair, one dwordx4
// store per thread in the transpose phase (store instrs 8 -> 3 per thread).
__global__ __launch_bounds__(256) void writhe_tile(const float* __restrict__ x,
                                                   float* __restrict__ out) {
    __shared__ __align__(16) float4 xs4[N];
    __shared__ __align__(16) float tsf[TILE * TSTRIDE];

    const int batch = blockIdx.y;

    // Coalesced float4 global read, stride-3 -> stride-4 repack into LDS.
    {
        const float4* src = (const float4*)(x + (size_t)batch * (N * 3));
        float* xsf = (float*)xs4;
        for (int i = threadIdx.x; i < (N * 3) / 4; i += blockDim.x) {
            float4 g = src[i];
            const int base = 4 * i;
            float vv[4] = {g.x, g.y, g.z, g.w};
#pragma unroll
            for (int j = 0; j < 4; ++j) {
                const int e = base + j;
                xsf[(e / 3) * 4 + (e % 3)] = vv[j];
            }
        }
    }

    // blockIdx.x -> (ti, tj), ti <= tj, among 16x16 tiles (136 pairs).
    int p = blockIdx.x;
    int ti = 0;
    while (p >= (N / TILE) - ti) { p -= (N / TILE) - ti; ++ti; }
    const int tj = ti + p;
    const bool diag = (ti == tj);

    __syncthreads();

    float* ob = out + (size_t)batch * (N * N);

    if (ti >= 1 && !diag) {
        // ---- fast path: index rule is unconditionally (gi-1, gj-1) ----
        const int cp = threadIdx.x & 15;  // column pair
        const int r = threadIdx.x >> 4;   // row in [0,16)
        const int gj0 = tj * TILE + 2 * cp;

        // 3 unique column points; halves share xs4[gj0].
        const float4 qa = xs4[gj0 - 1];
        const float4 qb = xs4[gj0];
        const float4 qc = xs4[gj0 + 1];
        const F3P P2 = pack_pt4(qa, qb);
        const F3P P3 = pack_pt4(qb, qc);

#pragma unroll
        for (int k = 0; k < 2; ++k) {
            const int rr = r + 16 * k;
            const int gi = ti * TILE + rr;
            const F3P P0 = splat_pt(xs4, gi - 1);
            const F3P P1 = splat_pt(xs4, gi);
            float2 wr = wr_core2(P0, P1, P2, P3);
            // adjacency guard (only adjacent tiles can violate hi >= lo+2)
            const float vx = (gj0 >= gi + 2) ? wr.x : 0.f;
            const float vy = (gj0 + 1 >= gi + 2) ? wr.y : 0.f;
            const float2 vv = make_float2(vx, vy);
            *(float2*)(ob + (size_t)gi * N + gj0) = vv;           // aligned 8B
            *(float2*)(tsf + rr * TSTRIDE + 2 * cp) = vv;          // aligned 8B
        }

        __syncthreads();
        // Transpose write: thread (r2, g) stores 4 consecutive columns of one row.
        {
            const int r2 = threadIdx.x & 31;
            const int g = threadIdx.x >> 5;  // 0..7
            float4 o;
            o.x = tsf[(4 * g + 0) * TSTRIDE + r2];
            o.y = tsf[(4 * g + 1) * TSTRIDE + r2];
            o.z = tsf[(4 * g + 2) * TSTRIDE + r2];
            o.w = tsf[(4 * g + 3) * TSTRIDE + r2];
            *(float4*)(ob + (size_t)(tj * TILE + r2) * N + ti * TILE + 4 * g) = o;
        }
    } else {
        // ---- generic path (diag + ti==0 tiles) ----
        const int c = threadIdx.x & 31;
        const int r0 = threadIdx.x >> 5;
        const int gj = tj * TILE + c;

#pragma unroll
        for (int k = 0; k < 2; ++k) {
            const int rA = r0 + 8 * k;
            const int rB = rA + 16;
            const int giA = ti * TILE + rA;
            const int giB = ti * TILE + rB;

            int aA, bA, aB, bB;
            bool vA, vB;
            elem_idx(giA, gj, aA, bA, vA);
            elem_idx(giB, gj, aB, bB, vB);

            F3P P0 = pack_pt(xs4, aA, aB);
            F3P P1 = pack_pt(xs4, aA + 1, aB + 1);
            F3P P2 = pack_pt(xs4, bA, bB);
            F3P P3 = pack_pt(xs4, bA + 1, bB + 1);

            float2 wr = wr_core2(P0, P1, P2, P3);
            const float vxA = vA ? wr.x : 0.f;
            const float vxB = vB ? wr.y : 0.f;

            ob[(size_t)giA * N + gj] = vxA;
            ob[(size_t)giB * N + gj] = vxB;
            if (!diag) {
                tsf[rA * TSTRIDE + c] = vxA;
                tsf[rB * TSTRIDE + c] = vxB;
            }
        }

        if (!diag) {
            __syncthreads();
#pragma unroll
            for (int k = 0; k < 4; ++k) {
                const int r2 = r0 + 8 * k;
                ob[(size_t)(tj * TILE + r2) * N + (ti * TILE + c)] = tsf[c * TSTRIDE + r2];
            }
        }
    }
}

extern "C" void kernel_launch(void* const* d_in, const int* in_sizes, int n_in,
                              void* d_out, int out_size, void* d_ws, size_t ws_size,
                              hipStream_t stream) {
    const float* x = (const float*)d_in[0];
    float* out = (float*)d_out;
    const int B = in_sizes[0] / (N * 3);

    const int ntiles = N / TILE;                   // 16
    const int npairs = ntiles * (ntiles + 1) / 2;  // 136

    dim3 block(256);
    dim3 grid(npairs, B);
    writhe_tile<<<grid, block, 0, stream>>>(x, out);
}